// Round 7
// baseline (1523.131 us; speedup 1.0000x reference)
//
#include <hip/hip_runtime.h>

// ---------------------------------------------------------------------------
// (B,T,D)=(4,8192,1024), TREE_DEPTH=10, NUM_NODES=1023.
//
// R7 = DIAGNOSTIC ROUND. Functionally identical to R6 (412.7us, passed).
// Motivation: R3->R6 A/B proved launch overhead ~1.3us/launch, so ~390us is
// interior to our kernels, but every static model sums to ~150-180us and the
// rocprof top-5 is masked by five ~80us workspace-poison fills -> we have
// NEVER seen a per-kernel duration. FLOORPAD: block (0,0,0) of every kernel
// spins ~95us on wall_clock64 (100MHz constant) before working. Each dispatch
// then lasts max(real, ~95us) > fills, so top-5 = our five slowest kernels
// with TRUE durations (where >95us) and true FETCH/WRITE/occupancy counters.
// _ord disambiguates the five k_level_mfma dispatches (L8..L4 in order).
// Readout: (a) all rows ~95-110 -> no hidden giant, cost is inter-kernel ->
// merge kernels next; (b) rows at 150-300 -> that kernel is the sink, its
// counters pick the fix. Correctness unchanged (spin is pure time).
// ---------------------------------------------------------------------------

#define NODES 1023
#define DIM   1024
#define K2    2048
#define NCHUNK 64
#define PAD_TICKS 9500   // ~95us at 100MHz wall clock

typedef short short8 __attribute__((ext_vector_type(8)));
typedef float floatx4 __attribute__((ext_vector_type(4)));

__device__ __forceinline__ void floorpad() {
    if (blockIdx.x == 0 && blockIdx.y == 0 && blockIdx.z == 0) {
        long long t0 = wall_clock64();
        int guard = 0;
        while (wall_clock64() - t0 < PAD_TICKS && guard < (1 << 26)) ++guard;
    }
}

__device__ __forceinline__ unsigned short f2bf(float f) {
    unsigned u = __float_as_uint(f);
    unsigned r = ((u >> 16) & 1u) + 0x7fffu;
    return (unsigned short)((u + r) >> 16);
}

#define GLD16(g, l)                                                            \
    __builtin_amdgcn_global_load_lds(                                          \
        (const __attribute__((address_space(1))) void*)(g),                    \
        (__attribute__((address_space(3))) void*)(l), 16, 0, 0)

// ------------------- fused W->bf16 convert + leaf pooling -------------------
__global__ __launch_bounds__(256) void k_prep(const float* __restrict__ W,
                                              unsigned short* __restrict__ Wb,
                                              const float* __restrict__ x,
                                              float* __restrict__ Sf,
                                              unsigned short* __restrict__ Sb) {
    floorpad();
    int bx = blockIdx.x;
    if (bx < 2048) {
        int i = (bx * 256 + threadIdx.x) * 4;
        float4 v = *(const float4*)(W + i);
        ushort4 o;
        o.x = f2bf(v.x); o.y = f2bf(v.y); o.z = f2bf(v.z); o.w = f2bf(v.w);
        *(ushort4*)(Wb + i) = o;
    } else {
        int idx = bx - 2048;
        int leaf = idx & 511;
        int b = idx >> 9;
        int d = threadIdx.x * 4;
        const float* xp = x + ((size_t)b * 8192 + (size_t)leaf * 8) * DIM + d;
        float4 s = {0.f, 0.f, 0.f, 0.f};
#pragma unroll
        for (int i = 0; i < 8; ++i) {
            float4 v = *(const float4*)(xp + (size_t)i * DIM);
            s.x += v.x; s.y += v.y; s.z += v.z; s.w += v.w;
        }
        s.x *= 0.125f; s.y *= 0.125f; s.z *= 0.125f; s.w *= 0.125f;
        size_t o = ((size_t)b * NODES + 511 + leaf) * DIM + d;
        *(float4*)(Sf + o) = s;
        ushort4 ob;
        ob.x = f2bf(s.x); ob.y = f2bf(s.y); ob.z = f2bf(s.z); ob.w = f2bf(s.w);
        *(ushort4*)(Sb + o) = ob;
    }
}

// --------------------------- MFMA level (L >= 4) -----------------------------
__global__ __launch_bounds__(256) void k_level_mfma(
    const unsigned short* __restrict__ SbIn, const unsigned short* __restrict__ Wb,
    const float* __restrict__ bt, float* __restrict__ Sf,
    unsigned short* __restrict__ SbOut, int L) {
    floorpad();
    const int lvl_start = (1 << L) - 1;
    const int child_start = (2 << L) - 1;
    const int mask = (1 << L) - 1;

    __shared__ __align__(16) unsigned short Al[3][4096];
    __shared__ __align__(16) unsigned short Bl[3][4096];

    const int t = threadIdx.x;
    const int lane = t & 63;
    const int w = t >> 6;
    const int wm = w >> 1, wn = w & 1;
    const int bm = blockIdx.y, bn = blockIdx.x;

    floatx4 acc[2][2];
#pragma unroll
    for (int i = 0; i < 2; ++i)
#pragma unroll
        for (int j = 0; j < 2; ++j) acc[i][j] = (floatx4){0.f, 0.f, 0.f, 0.f};

    const int trow = t >> 3;
    const int csw = ((t & 7) ^ (trow & 7)) * 8;

    const unsigned short* aptr[2];
#pragma unroll
    for (int p = 0; p < 2; ++p) {
        int rg = bm * 64 + p * 32 + trow;
        int bb = rg >> L;
        int nl = rg & mask;
        aptr[p] = SbIn + ((size_t)bb * NODES + child_start + 2 * nl) * DIM + csw;
    }
    const unsigned short* bptr[2];
#pragma unroll
    for (int p = 0; p < 2; ++p) {
        int rg = bn * 64 + p * 32 + trow;
        bptr[p] = Wb + (size_t)rg * K2 + csw;
    }

#define STAGE(buf, k0)                                                         \
    {                                                                          \
        _Pragma("unroll")                                                      \
        for (int p = 0; p < 2; ++p)                                            \
            GLD16(aptr[p] + (k0), &Al[buf][(p * 32 + w * 8) * 64]);            \
        _Pragma("unroll")                                                      \
        for (int p = 0; p < 2; ++p)                                            \
            GLD16(bptr[p] + (k0), &Bl[buf][(p * 32 + w * 8) * 64]);            \
    }

    const int rsel = lane & 15;
    const int jx = lane >> 4;
    const int swz = lane & 7;

#define COMP(bi)                                                               \
    {                                                                          \
        const char* Ab = (const char*)&Al[bi][0];                              \
        const char* Bb = (const char*)&Bl[bi][0];                              \
        _Pragma("unroll")                                                      \
        for (int ks = 0; ks < 2; ++ks) {                                       \
            short8 af[2], bf[2];                                               \
            _Pragma("unroll")                                                  \
            for (int i = 0; i < 2; ++i) {                                      \
                af[i] = *(const short8*)(Ab + (wm * 32 + i * 16 + rsel) * 128 +\
                                         (((ks * 4 + jx) ^ swz) << 4));        \
                bf[i] = *(const short8*)(Bb + (wn * 32 + i * 16 + rsel) * 128 +\
                                         (((ks * 4 + jx) ^ swz) << 4));        \
            }                                                                  \
            _Pragma("unroll")                                                  \
            for (int i = 0; i < 2; ++i)                                        \
                _Pragma("unroll")                                              \
                for (int j = 0; j < 2; ++j)                                    \
                    acc[i][j] = __builtin_amdgcn_mfma_f32_16x16x32_bf16(       \
                        af[i], bf[j], acc[i][j], 0, 0, 0);                     \
        }                                                                      \
    }

    STAGE(0, 0);
    STAGE(1, 64);
#pragma unroll 3
    for (int it = 0; it < 30; ++it) {
        asm volatile("s_waitcnt vmcnt(4)" ::: "memory");
        __builtin_amdgcn_s_barrier();
        STAGE((it + 2) % 3, (it + 2) * 64);
        COMP(it % 3);
    }
    asm volatile("s_waitcnt vmcnt(4)" ::: "memory");
    __builtin_amdgcn_s_barrier();
    COMP(0);
    asm volatile("s_waitcnt vmcnt(0)" ::: "memory");
    __builtin_amdgcn_s_barrier();
    COMP(1);
#undef STAGE
#undef COMP

    const float* btL = bt + (size_t)L * DIM;
#pragma unroll
    for (int i = 0; i < 2; ++i)
#pragma unroll
        for (int j = 0; j < 2; ++j)
#pragma unroll
            for (int r = 0; r < 4; ++r) {
                int m = bm * 64 + wm * 32 + i * 16 + (lane >> 4) * 4 + r;
                int n = bn * 64 + wn * 32 + j * 16 + (lane & 15);
                float v = acc[i][j][r];
                float o = (v - btL[n] > 0.f) ? v : 0.f;
                int bb = m >> L;
                int nl = m & mask;
                size_t idx = ((size_t)bb * NODES + lvl_start + nl) * DIM + n;
                Sf[idx] = o;
                if (L > 4) SbOut[idx] = f2bf(o);
            }
}

// ------------------------- small level (L <= 3), fp32 ------------------------
__global__ __launch_bounds__(256) void k_level_small(
    const float* __restrict__ SfIn, const float* __restrict__ W,
    const float* __restrict__ bt, float* __restrict__ Sf, int L) {
    floorpad();
    int r = blockIdx.y;
    int b = r >> L;
    int nl = r & ((1 << L) - 1);
    int node = (1 << L) - 1 + nl;
    int child = 2 * node + 1;
    const float* A = SfIn + ((size_t)b * NODES + child) * DIM;

    __shared__ float Alds[K2];
    int t = threadIdx.x;
    ((float4*)Alds)[t * 2] = ((const float4*)A)[t * 2];
    ((float4*)Alds)[t * 2 + 1] = ((const float4*)A)[t * 2 + 1];
    __syncthreads();

    int lane = t & 63;
    int wv = t >> 6;
#pragma unroll 4
    for (int q = 0; q < 16; ++q) {
        int dd = blockIdx.x * 64 + wv * 16 + q;
        const float4* Wr = (const float4*)(W + (size_t)dd * K2);
        const float4* Ar = (const float4*)Alds;
        float s = 0.f;
#pragma unroll
        for (int j = 0; j < 8; ++j) {
            float4 wv4 = Wr[j * 64 + lane];
            float4 av = Ar[j * 64 + lane];
            s += wv4.x * av.x + wv4.y * av.y + wv4.z * av.z + wv4.w * av.w;
        }
#pragma unroll
        for (int o = 32; o > 0; o >>= 1) s += __shfl_xor(s, o, 64);
        if (lane == 0) {
            float u = s - bt[(size_t)L * DIM + dd];
            float o = (u > 0.f) ? s : 0.f;
            Sf[((size_t)b * NODES + node) * DIM + dd] = o;
        }
    }
}

// ---------------- softmax mixture, phase A: partial sums per chunk -----------
__global__ __launch_bounds__(256) void k_mixture_part(const float* __restrict__ nw,
                                                      const float* __restrict__ Sf,
                                                      float* __restrict__ part) {
    floorpad();
    int d = blockIdx.x * 256 + threadIdx.x;
    int c = blockIdx.y;
    int n0i = c * 16;
    int n1i = n0i + 16 < NODES ? n0i + 16 : NODES;
    float denom = 0.f, s0 = 0.f, s1 = 0.f, s2 = 0.f, s3 = 0.f;
    for (int n = n0i; n < n1i; ++n) {
        float wv = __expf(nw[(size_t)n * DIM + d]);
        denom += wv;
        s0 += wv * Sf[((size_t)0 * NODES + n) * DIM + d];
        s1 += wv * Sf[((size_t)1 * NODES + n) * DIM + d];
        s2 += wv * Sf[((size_t)2 * NODES + n) * DIM + d];
        s3 += wv * Sf[((size_t)3 * NODES + n) * DIM + d];
    }
    size_t base = ((size_t)c * 5) * DIM + d;
    part[base]           = denom;
    part[base + 1 * DIM] = s0;
    part[base + 2 * DIM] = s1;
    part[base + 3 * DIM] = s2;
    part[base + 4 * DIM] = s3;
}

// ---------------- softmax mixture, phase B: reduce chunks --------------------
__global__ __launch_bounds__(256) void k_mixture_red(const float* __restrict__ part,
                                                     float* __restrict__ mix) {
    floorpad();
    int d = blockIdx.x * 256 + threadIdx.x;
    float denom = 0.f, s0 = 0.f, s1 = 0.f, s2 = 0.f, s3 = 0.f;
#pragma unroll 8
    for (int c = 0; c < NCHUNK; ++c) {
        size_t base = ((size_t)c * 5) * DIM + d;
        denom += part[base];
        s0 += part[base + 1 * DIM];
        s1 += part[base + 2 * DIM];
        s2 += part[base + 3 * DIM];
        s3 += part[base + 4 * DIM];
    }
    float inv = 1.f / denom;
    mix[0 * DIM + d] = s0 * inv;
    mix[1 * DIM + d] = s1 * inv;
    mix[2 * DIM + d] = s2 * inv;
    mix[3 * DIM + d] = s3 * inv;
}

// --------------------- out = rmsnorm(x + mixture) * rms_w --------------------
__global__ __launch_bounds__(256) void k_final(const float* __restrict__ x,
                                               const float* __restrict__ mix,
                                               const float* __restrict__ rw,
                                               float* __restrict__ out) {
    floorpad();
    int row = blockIdx.x;
    int b = row >> 13;
    size_t base = (size_t)row * DIM;
    int t = threadIdx.x;
    float4 xv = *(const float4*)(x + base + t * 4);
    float4 mv = *(const float4*)(mix + b * DIM + t * 4);
    float4 v = {xv.x + mv.x, xv.y + mv.y, xv.z + mv.z, xv.w + mv.w};
    float ss = v.x * v.x + v.y * v.y + v.z * v.z + v.w * v.w;
#pragma unroll
    for (int o = 32; o > 0; o >>= 1) ss += __shfl_xor(ss, o, 64);
    __shared__ float wsum[4];
    int lane = t & 63, wv_ = t >> 6;
    if (lane == 0) wsum[wv_] = ss;
    __syncthreads();
    float tot = wsum[0] + wsum[1] + wsum[2] + wsum[3];
    float inv = 1.f / sqrtf(tot * (1.f / 1024.f) + 1.1920929e-7f);
    float4 rwv = *(const float4*)(rw + t * 4);
    float4 o4 = {v.x * inv * rwv.x, v.y * inv * rwv.y, v.z * inv * rwv.z,
                 v.w * inv * rwv.w};
    *(float4*)(out + base + t * 4) = o4;
}

// ----------------------------------------------------------------------------
extern "C" void kernel_launch(void* const* d_in, const int* in_sizes, int n_in,
                              void* d_out, int out_size, void* d_ws, size_t ws_size,
                              hipStream_t stream) {
    (void)in_sizes; (void)n_in; (void)out_size; (void)ws_size;
    const float* x  = (const float*)d_in[0];
    const float* W  = (const float*)d_in[1];
    const float* nw = (const float*)d_in[2];
    const float* bt = (const float*)d_in[3];
    const float* rw = (const float*)d_in[5];
    float* out = (float*)d_out;

    char* ws = (char*)d_ws;
    const size_t SF_BYTES = (size_t)4 * NODES * DIM * 4;
    const size_t SB_BYTES = (size_t)4 * NODES * DIM * 2;
    const size_t WB_BYTES = (size_t)K2 * DIM * 2;
    const size_t MIX_BYTES = (size_t)4 * DIM * 4;
    const size_t BASE = SF_BYTES + SB_BYTES + WB_BYTES + MIX_BYTES;
    float* Sf = (float*)ws;
    unsigned short* Sb = (unsigned short*)(ws + SF_BYTES);
    unsigned short* Wb = (unsigned short*)(ws + SF_BYTES + SB_BYTES);
    float* mix = (float*)(ws + SF_BYTES + SB_BYTES + WB_BYTES);
    float* part = (float*)(ws + BASE);

    k_prep<<<4096, 256, 0, stream>>>(W, Wb, x, Sf, Sb);

    for (int L = 8; L >= 4; --L) {
        int Mt = (4 << L) >> 6;
        k_level_mfma<<<dim3(16, Mt), 256, 0, stream>>>(Sb, Wb, bt, Sf, Sb, L);
    }
    for (int L = 3; L >= 0; --L) {
        int R = 4 << L;
        k_level_small<<<dim3(16, R), 256, 0, stream>>>(Sf, W, bt, Sf, L);
    }
    k_mixture_part<<<dim3(4, NCHUNK), 256, 0, stream>>>(nw, Sf, part);
    k_mixture_red<<<4, 256, 0, stream>>>(part, mix);
    k_final<<<32768, 256, 0, stream>>>(x, mix, rw, out);
}